// Round 2
// baseline (899.538 us; speedup 1.0000x reference)
//
#include <hip/hip_runtime.h>

// Problem constants: B=32, H=24, N=500, F_IN=64, F_OUT=4, M=16, O=H*N=12000
#define Bc   32
#define Oc   12000
#define Mc   16

// R3: R1 structure (LDS-staged weights, o-fast lanes, x in regs) with the
// latency fixes R1 lacked. R1 post-mortem: no pipe >31% busy -> latency-bound
// at 18% occupancy (41.5KB LDS = 3 blocks/CU) with a 4-deep epilogue.
// R2 post-mortem: no-LDS broadcast loads = 16-64 distinct lines per VMEM
// instr -> TA/scatter-bound (183us). Weight reuse must stay in LDS.
//
// Changes vs R1:
//  (1) f-loop chunked 4x16: stage one 16-f weight slice at a time.
//      LDS 41.5KB -> 11.1KB. Padded strides (65/17 float4 per o) keep the
//      8 distinct oi addresses tiling all 8 bank-quads; bi lanes broadcast.
//  (2) x loaded 4 float4 per chunk (not 16 upfront) -> lower VGPR;
//      __launch_bounds__(256,4) -> 4 blocks/CU resident (was 3, avg occ 18%).
//  (3) epilogue: all 16 eps loads issued before any compute -> 16-deep MLP
//      against ~900cy HBM latency (was 4-deep interleaved).
//  (4) per-chunk x loads issue post-barrier, pre-stage: overlap staging.
__global__ __launch_bounds__(256, 4) void mgr_fused_kernel(
    const float* __restrict__ x,        // [B, O, 64]
    const float* __restrict__ mu_w,     // [O, 64, 4]
    const float* __restrict__ mu_b,     // [O, 4]
    const float* __restrict__ sigma_w,  // [O, 64, 16]
    const float* __restrict__ sigma_b,  // [O, 16]
    const float* __restrict__ eps,      // [M, B, O, 4]
    float* __restrict__ out)            // [M, B, O, 4]
{
    // One 16-f chunk of weights for the block's 8 o's.
    __shared__ float4 s_sw4[8 * 65];   // sigma chunk: [oi][p=fl*4+k], stride 65 (64+1 pad)
    __shared__ float4 s_muw4[8 * 17];  // mu chunk:    [oi][fl],        stride 17 (16+1 pad)
    __shared__ float4 s_mub4[8];
    __shared__ float4 s_sb4[8 * 4];

    const int tid = threadIdx.x;
    const int blk = blockIdx.x;
    const int oi  = tid & 7;           // o fast in lane index -> coalesced eps/out/x
    const int bi  = tid >> 3;          // 0..31
    const int o   = blk * 8 + oi;

    const float4* __restrict__ sw_g  = reinterpret_cast<const float4*>(sigma_w) + blk * 8 * 256;
    const float4* __restrict__ muw_g = reinterpret_cast<const float4*>(mu_w)    + blk * 8 * 64;
    const float4* __restrict__ x4    = reinterpret_cast<const float4*>(x) + (bi * Oc + o) * 16;

    float4 amu, as0, as1, as2, as3;

    #pragma unroll
    for (int c = 0; c < 4; ++c) {
        if (c > 0) __syncthreads();    // previous chunk fully consumed before overwrite

        // x slice for this chunk: independent of LDS, issues before staging
        // loads so it completes under the stage + barrier.
        const float4 xv0 = x4[c * 4 + 0];
        const float4 xv1 = x4[c * 4 + 1];
        const float4 xv2 = x4[c * 4 + 2];
        const float4 xv3 = x4[c * 4 + 3];

        // ---- stage sigma chunk: 512 float4, 2/thread, 1KB-contiguous per o ----
        {
            const int t0 = tid, t1 = tid + 256;
            const float4 v0 = sw_g[(t0 >> 6) * 256 + c * 64 + (t0 & 63)];
            const float4 v1 = sw_g[(t1 >> 6) * 256 + c * 64 + (t1 & 63)];
            s_sw4[(t0 >> 6) * 65 + (t0 & 63)] = v0;
            s_sw4[(t1 >> 6) * 65 + (t1 & 63)] = v1;
        }
        // ---- stage mu chunk: 128 float4 ----
        if (tid < 128) {
            const int oL = tid >> 4, fl = tid & 15;
            s_muw4[oL * 17 + fl] = muw_g[oL * 64 + c * 16 + fl];
        }
        if (c == 0) {
            if (tid < 32) {
                s_sb4[tid] = reinterpret_cast<const float4*>(sigma_b)[blk * 32 + tid];
            } else if (tid < 40) {
                s_mub4[tid - 32] = reinterpret_cast<const float4*>(mu_b)[blk * 8 + (tid - 32)];
            }
        }
        __syncthreads();

        if (c == 0) {
            amu = s_mub4[oi];
            as0 = s_sb4[oi * 4 + 0];
            as1 = s_sb4[oi * 4 + 1];
            as2 = s_sb4[oi * 4 + 2];
            as3 = s_sb4[oi * 4 + 3];
        }

        const float4* __restrict__ muw = &s_muw4[oi * 17];
        const float4* __restrict__ sw  = &s_sw4[oi * 65];

        #pragma unroll
        for (int fq = 0; fq < 4; ++fq) {
            const float4 xq = (fq == 0) ? xv0 : (fq == 1) ? xv1 : (fq == 2) ? xv2 : xv3;
            #pragma unroll
            for (int fi = 0; fi < 4; ++fi) {
                const int fl = fq * 4 + fi;
                const float xs = (fi == 0) ? xq.x : (fi == 1) ? xq.y : (fi == 2) ? xq.z : xq.w;
                float4 w = muw[fl];
                amu.x = fmaf(xs, w.x, amu.x);
                amu.y = fmaf(xs, w.y, amu.y);
                amu.z = fmaf(xs, w.z, amu.z);
                amu.w = fmaf(xs, w.w, amu.w);
                float4 s;
                s = sw[4 * fl + 0];
                as0.x = fmaf(xs, s.x, as0.x); as0.y = fmaf(xs, s.y, as0.y);
                as0.z = fmaf(xs, s.z, as0.z); as0.w = fmaf(xs, s.w, as0.w);
                s = sw[4 * fl + 1];
                as1.x = fmaf(xs, s.x, as1.x); as1.y = fmaf(xs, s.y, as1.y);
                as1.z = fmaf(xs, s.z, as1.z); as1.w = fmaf(xs, s.w, as1.w);
                s = sw[4 * fl + 2];
                as2.x = fmaf(xs, s.x, as2.x); as2.y = fmaf(xs, s.y, as2.y);
                as2.z = fmaf(xs, s.z, as2.z); as2.w = fmaf(xs, s.w, as2.w);
                s = sw[4 * fl + 3];
                as3.x = fmaf(xs, s.x, as3.x); as3.y = fmaf(xs, s.y, as3.y);
                as3.z = fmaf(xs, s.z, as3.z); as3.w = fmaf(xs, s.w, as3.w);
            }
        }
    }

    // ---- epilogue: batch ALL 16 eps loads (16-deep MLP), then compute+store ----
    const float4* __restrict__ eps4 = reinterpret_cast<const float4*>(eps);
    float4* __restrict__ out4 = reinterpret_cast<float4*>(out);

    float4 e[16];
    #pragma unroll
    for (int m = 0; m < Mc; ++m)
        e[m] = eps4[(m * Bc + bi) * Oc + o];

    #pragma unroll
    for (int m = 0; m < Mc; ++m) {
        const int idx = (m * Bc + bi) * Oc + o;
        float4 r;
        r.x = amu.x + as0.x * e[m].x + as0.y * e[m].y + as0.z * e[m].z + as0.w * e[m].w;
        r.y = amu.y + as1.x * e[m].x + as1.y * e[m].y + as1.z * e[m].z + as1.w * e[m].w;
        r.z = amu.z + as2.x * e[m].x + as2.y * e[m].y + as2.z * e[m].z + as2.w * e[m].w;
        r.w = amu.w + as3.x * e[m].x + as3.y * e[m].y + as3.z * e[m].z + as3.w * e[m].w;
        out4[idx] = r;
    }
}

extern "C" void kernel_launch(void* const* d_in, const int* in_sizes, int n_in,
                              void* d_out, int out_size, void* d_ws, size_t ws_size,
                              hipStream_t stream) {
    const float* x       = (const float*)d_in[0];
    const float* mu_w    = (const float*)d_in[1];
    const float* mu_b    = (const float*)d_in[2];
    const float* sigma_w = (const float*)d_in[3];
    const float* sigma_b = (const float*)d_in[4];
    const float* eps     = (const float*)d_in[5];
    float* out = (float*)d_out;

    dim3 grid(Oc / 8);   // 1500 blocks
    dim3 block(256);
    mgr_fused_kernel<<<grid, block, 0, stream>>>(x, mu_w, mu_b, sigma_w, sigma_b, eps, out);
}

// Round 3
// 616.684 us; speedup vs baseline: 1.4587x; 1.4587x over previous
//
#include <hip/hip_runtime.h>

// Problem constants: B=32, H=24, N=500, F_IN=64, F_OUT=4, M=16, O=H*N=12000
#define Bc   32
#define Oc   12000
#define Mc   16

// R4 = R3's chunked structure with the spill eliminated.
// R3 post-mortem: __launch_bounds__(256,4) forced VGPR=64 -> e[16]+acc+xv
// spilled to scratch: WRITE_SIZE 1.5GB (16x output), FETCH 884MB (7x), 733us.
// R1 post-mortem: latency-bound, 41.5KB LDS capped 3 blocks/CU, occ 18%.
//
// This version:
//  (1) plain __launch_bounds__(256) (R1's proven no-spill setting, VGPR~120);
//      occupancy gain comes from LDS 41.5KB -> 11.25KB => 4 blocks/CU
//      (VGPR<=128 is the binding limit).
//  (2) f-loop chunked 4x16: stage one 16-f weight slice at a time. Padded
//      strides (65/17 float4 per o): the 8 oi addresses of a wave-wide
//      ds_read_b128 start 4 banks apart -> exactly tile 32 banks, bi-lanes
//      broadcast. Conflict-free.
//  (3) epilogue: two batches of 8 eps loads (32 regs in flight, not 64) ->
//      8-deep MLP against ~900cy HBM latency without busting the 128 budget.
//  (4) biases loaded straight from global (bi-lanes same-address broadcast);
//      no LDS or branch for them.
__global__ __launch_bounds__(256) void mgr_fused_kernel(
    const float* __restrict__ x,        // [B, O, 64]
    const float* __restrict__ mu_w,     // [O, 64, 4]
    const float* __restrict__ mu_b,     // [O, 4]
    const float* __restrict__ sigma_w,  // [O, 64, 16]
    const float* __restrict__ sigma_b,  // [O, 16]
    const float* __restrict__ eps,      // [M, B, O, 4]
    float* __restrict__ out)            // [M, B, O, 4]
{
    __shared__ float4 s_sw4[8 * 65];   // sigma chunk: [oi][fl*4+k], stride 65
    __shared__ float4 s_muw4[8 * 17];  // mu chunk:    [oi][fl],     stride 17

    const int tid = threadIdx.x;
    const int blk = blockIdx.x;
    const int oi  = tid & 7;           // o fast in lanes -> coalesced eps/out
    const int bi  = tid >> 3;          // 0..31
    const int o   = blk * 8 + oi;

    const float4* __restrict__ sw_g  = reinterpret_cast<const float4*>(sigma_w) + blk * 2048;
    const float4* __restrict__ muw_g = reinterpret_cast<const float4*>(mu_w)    + blk * 512;
    const float4* __restrict__ x4    = reinterpret_cast<const float4*>(x) + (bi * Oc + o) * 16;

    // bias init straight from global: oi-contiguous, bi-lanes broadcast
    float4 amu = reinterpret_cast<const float4*>(mu_b)[o];
    float4 as0 = reinterpret_cast<const float4*>(sigma_b)[o * 4 + 0];
    float4 as1 = reinterpret_cast<const float4*>(sigma_b)[o * 4 + 1];
    float4 as2 = reinterpret_cast<const float4*>(sigma_b)[o * 4 + 2];
    float4 as3 = reinterpret_cast<const float4*>(sigma_b)[o * 4 + 3];

    #pragma unroll
    for (int c = 0; c < 4; ++c) {
        if (c > 0) __syncthreads();    // previous chunk consumed before overwrite

        // x slice for this chunk (64B contiguous per thread); independent of
        // LDS -> overlaps the staging loads + barrier.
        const float4 xv0 = x4[c * 4 + 0];
        const float4 xv1 = x4[c * 4 + 1];
        const float4 xv2 = x4[c * 4 + 2];
        const float4 xv3 = x4[c * 4 + 3];

        // ---- stage sigma chunk: 512 float4, 2/thread, coalesced ----
        {
            const int t0 = tid, t1 = tid + 256;
            const float4 v0 = sw_g[(t0 >> 6) * 256 + c * 64 + (t0 & 63)];
            const float4 v1 = sw_g[(t1 >> 6) * 256 + c * 64 + (t1 & 63)];
            s_sw4[(t0 >> 6) * 65 + (t0 & 63)] = v0;
            s_sw4[(t1 >> 6) * 65 + (t1 & 63)] = v1;
        }
        // ---- stage mu chunk: 128 float4 ----
        if (tid < 128) {
            const int oL = tid >> 4, fl = tid & 15;
            s_muw4[oL * 17 + fl] = muw_g[oL * 64 + c * 16 + fl];
        }
        __syncthreads();

        const float4* __restrict__ muw = &s_muw4[oi * 17];
        const float4* __restrict__ sw  = &s_sw4[oi * 65];

        #pragma unroll
        for (int fq = 0; fq < 4; ++fq) {
            const float4 xq = (fq == 0) ? xv0 : (fq == 1) ? xv1 : (fq == 2) ? xv2 : xv3;
            #pragma unroll
            for (int fi = 0; fi < 4; ++fi) {
                const int fl = fq * 4 + fi;
                const float xs = (fi == 0) ? xq.x : (fi == 1) ? xq.y : (fi == 2) ? xq.z : xq.w;
                float4 w = muw[fl];
                amu.x = fmaf(xs, w.x, amu.x);
                amu.y = fmaf(xs, w.y, amu.y);
                amu.z = fmaf(xs, w.z, amu.z);
                amu.w = fmaf(xs, w.w, amu.w);
                float4 s;
                s = sw[4 * fl + 0];
                as0.x = fmaf(xs, s.x, as0.x); as0.y = fmaf(xs, s.y, as0.y);
                as0.z = fmaf(xs, s.z, as0.z); as0.w = fmaf(xs, s.w, as0.w);
                s = sw[4 * fl + 1];
                as1.x = fmaf(xs, s.x, as1.x); as1.y = fmaf(xs, s.y, as1.y);
                as1.z = fmaf(xs, s.z, as1.z); as1.w = fmaf(xs, s.w, as1.w);
                s = sw[4 * fl + 2];
                as2.x = fmaf(xs, s.x, as2.x); as2.y = fmaf(xs, s.y, as2.y);
                as2.z = fmaf(xs, s.z, as2.z); as2.w = fmaf(xs, s.w, as2.w);
                s = sw[4 * fl + 3];
                as3.x = fmaf(xs, s.x, as3.x); as3.y = fmaf(xs, s.y, as3.y);
                as3.z = fmaf(xs, s.z, as3.z); as3.w = fmaf(xs, s.w, as3.w);
            }
        }
    }

    // ---- epilogue: 2 batches of 8 (8-deep eps MLP, 32 regs in flight) ----
    const float4* __restrict__ eps4 = reinterpret_cast<const float4*>(eps);
    float4* __restrict__ out4 = reinterpret_cast<float4*>(out);

    #pragma unroll
    for (int h = 0; h < 2; ++h) {
        float4 e[8];
        #pragma unroll
        for (int m = 0; m < 8; ++m)
            e[m] = eps4[((h * 8 + m) * Bc + bi) * Oc + o];
        #pragma unroll
        for (int m = 0; m < 8; ++m) {
            const int idx = ((h * 8 + m) * Bc + bi) * Oc + o;
            float4 r;
            r.x = amu.x + as0.x * e[m].x + as0.y * e[m].y + as0.z * e[m].z + as0.w * e[m].w;
            r.y = amu.y + as1.x * e[m].x + as1.y * e[m].y + as1.z * e[m].z + as1.w * e[m].w;
            r.z = amu.z + as2.x * e[m].x + as2.y * e[m].y + as2.z * e[m].z + as2.w * e[m].w;
            r.w = amu.w + as3.x * e[m].x + as3.y * e[m].y + as3.z * e[m].z + as3.w * e[m].w;
            out4[idx] = r;
        }
    }
}

extern "C" void kernel_launch(void* const* d_in, const int* in_sizes, int n_in,
                              void* d_out, int out_size, void* d_ws, size_t ws_size,
                              hipStream_t stream) {
    const float* x       = (const float*)d_in[0];
    const float* mu_w    = (const float*)d_in[1];
    const float* mu_b    = (const float*)d_in[2];
    const float* sigma_w = (const float*)d_in[3];
    const float* sigma_b = (const float*)d_in[4];
    const float* eps     = (const float*)d_in[5];
    float* out = (float*)d_out;

    dim3 grid(Oc / 8);   // 1500 blocks
    dim3 block(256);
    mgr_fused_kernel<<<grid, block, 0, stream>>>(x, mu_w, mu_b, sigma_w, sigma_b, eps, out);
}